// Round 4
// baseline (285.433 us; speedup 1.0000x reference)
//
#include <hip/hip_runtime.h>

// QuantizedLinear(5, 10, bits=2): out[N,10] = x[N,5] @ w_deq.T + bias
// Memory-bound: 80 MB read + 160 MB write -> ~38 us floor @ 6.3 TB/s.
//
// History: R1 225 (2 blk/CU LDS) | R2 237 (direct strided) | R3 211.6
//   (coalesced scalar, 8 blk/CU, NT) | R4 219.3 (float4, 5 blk/CU) |
//   R6 222.5 (persistent double-buffered, counted vmcnt, 1x dequant).
//   Six structures within +-6% -> kernel schedule is NOT the limiter.
// R7 (THIS IS A MEASUREMENT PROBE, NOT AN OPTIMIZATION): the qlinear
//   dispatch has never appeared in the top-5 counter rows (all fills at
//   ~97 us), so its true duration K and counters are unknown. Repeat the
//   R3 body 3x in-kernel (idempotent re-load/re-store, memory clobber
//   defeats hoisting/DCE) so the dispatch runs ~3K >= 114 us and enters
//   the top-5 with its real FETCH/WRITE/BW/occupancy row.
//   Decision: 3K in [115,165] -> K~40-55 -> harness-floor confirmed,
//   revert to R3 and declare roofline. 3K >= 210 -> ~50 us addressable,
//   diagnose from the kernel's own counter row.

constexpr int IN_F   = 5;
constexpr int OUT_F  = 10;
constexpr int BLOCK  = 256;
constexpr int TOK    = 256;          // tokens per block == threads per block
constexpr int REPEAT = 3;            // measurement multiplier

__global__ __launch_bounds__(BLOCK) void qlinear_kernel(
    const float* __restrict__ x,
    const float* __restrict__ w,
    const float* __restrict__ bias,
    float* __restrict__ out,
    int n_tokens)
{
    __shared__ float wdq[OUT_F * IN_F];
    __shared__ float bsh[OUT_F];
    __shared__ float xs[TOK * IN_F];     // 5 KB
    __shared__ float os[TOK * OUT_F];    // 10 KB

    const int tid = threadIdx.x;

    const long tok0 = (long)blockIdx.x * TOK;
    const bool full = (tok0 + TOK) <= (long)n_tokens;
    const long xbase = tok0 * IN_F;
    const long obase = tok0 * OUT_F;

    for (int rep = 0; rep < REPEAT; ++rep) {
        // force re-execution of loads/stores each rep (probe semantics)
        asm volatile("" ::: "memory");

        // threads 0..9: dequantize one weight row each (bits=2: qmax=1, qmin=-2)
        if (tid < OUT_F) {
            float row[IN_F];
            float mx = 0.0f;
            #pragma unroll
            for (int j = 0; j < IN_F; ++j) {
                row[j] = w[tid * IN_F + j];
                mx = fmaxf(mx, fabsf(row[j]));
            }
            const float scale = fmaxf(mx, 1e-8f);
            #pragma unroll
            for (int j = 0; j < IN_F; ++j) {
                float q = rintf(row[j] / scale);   // round-half-even like jnp
                q = fminf(fmaxf(q, -2.0f), 1.0f);
                wdq[tid * IN_F + j] = q * scale;
            }
            bsh[tid] = bias[tid];
        }

        // --- stage x tile: 1280 floats, 5 coalesced dword loads/thread ---
        if (full) {
            #pragma unroll
            for (int i = 0; i < IN_F; ++i) {
                const int k = i * BLOCK + tid;
                xs[k] = __builtin_nontemporal_load(x + xbase + k);
            }
        } else {
            const long xtotal = (long)n_tokens * IN_F;
            #pragma unroll
            for (int i = 0; i < IN_F; ++i) {
                const int k = i * BLOCK + tid;
                const long gi = xbase + k;
                xs[k] = (gi < xtotal) ? x[gi] : 0.0f;
            }
        }
        __syncthreads();

        // --- compute: 1 token/thread; xs read stride 5 (odd, conflict-free) ---
        {
            float xv[IN_F];
            #pragma unroll
            for (int j = 0; j < IN_F; ++j) xv[j] = xs[tid * IN_F + j];
            #pragma unroll
            for (int o = 0; o < OUT_F; ++o) {
                float acc = bsh[o];
                #pragma unroll
                for (int j = 0; j < IN_F; ++j)
                    acc = fmaf(xv[j], wdq[o * IN_F + j], acc);
                os[tid * OUT_F + o] = acc;   // 4-way bank conflict, negligible
            }
        }
        __syncthreads();

        // --- store out tile: 2560 floats, 10 coalesced dword stores/thread ---
        if (full) {
            #pragma unroll
            for (int i = 0; i < OUT_F; ++i) {
                const int k = i * BLOCK + tid;
                __builtin_nontemporal_store(os[k], out + obase + k);
            }
        } else {
            const long ototal = (long)n_tokens * OUT_F;
            #pragma unroll
            for (int i = 0; i < OUT_F; ++i) {
                const int k = i * BLOCK + tid;
                const long gi = obase + k;
                if (gi < ototal) out[gi] = os[k];
            }
        }
        __syncthreads();   // os/xs safe to overwrite next rep
    }
}

extern "C" void kernel_launch(void* const* d_in, const int* in_sizes, int n_in,
                              void* d_out, int out_size, void* d_ws, size_t ws_size,
                              hipStream_t stream) {
    const float* x    = (const float*)d_in[0];   // [N, 5]
    const float* wgt  = (const float*)d_in[1];   // [10, 5]
    const float* bias = (const float*)d_in[2];   // [10]
    float* out = (float*)d_out;                  // [N, 10]

    const int n_tokens = in_sizes[0] / IN_F;          // 4,000,000
    const int blocks   = (n_tokens + TOK - 1) / TOK;  // 15625, no tail

    qlinear_kernel<<<blocks, BLOCK, 0, stream>>>(x, wgt, bias, out, n_tokens);
}

// Round 5
// 212.534 us; speedup vs baseline: 1.3430x; 1.3430x over previous
//
#include <hip/hip_runtime.h>

// QuantizedLinear(5, 10, bits=2): out[N,10] = x[N,5] @ w_deq.T + bias
// Memory-bound: 80 MB read + 160 MB write -> ~38 us floor @ 6.3 TB/s.
//
// FINAL (R3 structure, re-validated by the R7 measurement probe):
//   R7 ran this exact body 3x in-kernel -> dispatch 117.2 us = 39.1 us/pass,
//   with WRITE_SIZE = 151.3 MB/rep (== minimal 152.6 MiB out tensor),
//   FETCH ~ 80 MB cold (L3 absorbed re-reads), bank conflicts 0,
//   VALUBusy 29%, occupancy 81%. Cold-pass effective stream rate:
//   240 MB / 39.1 us = 6.14 TB/s = 97.5% of the 6.29 TB/s achievable
//   HBM ceiling (m13 float4-copy microbench). This kernel is at the
//   memory roofline.
//
//   dur_us (~212) accounting: kernel ~39 + harness re-poison fill ~97
//   (640 MB @ 6.5 TB/s, fixed) + ~75 of harness memsets/launch gaps.
//   Six alternative structures (LDS tiles 2-8 blk/CU, float4 staging,
//   persistent double-buffered counted-vmcnt pipeline) all landed within
//   +-6% of total — confirming everything since R3 was noise around a
//   saturated 39 us kernel inside a ~212 us fixed envelope.

constexpr int IN_F  = 5;
constexpr int OUT_F = 10;
constexpr int BLOCK = 256;
constexpr int TOK   = 256;           // tokens per block == threads per block

__global__ __launch_bounds__(BLOCK) void qlinear_kernel(
    const float* __restrict__ x,
    const float* __restrict__ w,
    const float* __restrict__ bias,
    float* __restrict__ out,
    int n_tokens)
{
    __shared__ float wdq[OUT_F * IN_F];
    __shared__ float bsh[OUT_F];
    __shared__ float xs[TOK * IN_F];     // 5 KB
    __shared__ float os[TOK * OUT_F];    // 10 KB

    const int tid = threadIdx.x;

    // threads 0..9: dequantize one weight row each (bits=2: qmax=1, qmin=-2)
    if (tid < OUT_F) {
        float row[IN_F];
        float mx = 0.0f;
        #pragma unroll
        for (int j = 0; j < IN_F; ++j) {
            row[j] = w[tid * IN_F + j];
            mx = fmaxf(mx, fabsf(row[j]));
        }
        const float scale = fmaxf(mx, 1e-8f);
        #pragma unroll
        for (int j = 0; j < IN_F; ++j) {
            float q = rintf(row[j] / scale);       // round-half-even like jnp
            q = fminf(fmaxf(q, -2.0f), 1.0f);
            wdq[tid * IN_F + j] = q * scale;
        }
        bsh[tid] = bias[tid];
    }

    const long tok0 = (long)blockIdx.x * TOK;
    const bool full = (tok0 + TOK) <= (long)n_tokens;
    const long xbase = tok0 * IN_F;
    const long obase = tok0 * OUT_F;

    // --- stage x tile: 1280 floats, 5 coalesced dword loads/thread ---
    if (full) {
        #pragma unroll
        for (int i = 0; i < IN_F; ++i) {
            const int k = i * BLOCK + tid;
            xs[k] = __builtin_nontemporal_load(x + xbase + k);
        }
    } else {
        const long xtotal = (long)n_tokens * IN_F;
        #pragma unroll
        for (int i = 0; i < IN_F; ++i) {
            const int k = i * BLOCK + tid;
            const long gi = xbase + k;
            xs[k] = (gi < xtotal) ? x[gi] : 0.0f;
        }
    }
    __syncthreads();

    // --- compute: 1 token/thread; xs read stride 5 (odd, conflict-free) ---
    {
        float xv[IN_F];
        #pragma unroll
        for (int j = 0; j < IN_F; ++j) xv[j] = xs[tid * IN_F + j];
        #pragma unroll
        for (int o = 0; o < OUT_F; ++o) {
            float acc = bsh[o];
            #pragma unroll
            for (int j = 0; j < IN_F; ++j)
                acc = fmaf(xv[j], wdq[o * IN_F + j], acc);
            os[tid * OUT_F + o] = acc;   // 4-way bank conflict, negligible
        }
    }
    __syncthreads();

    // --- store out tile: 2560 floats, 10 coalesced dword stores/thread ---
    if (full) {
        #pragma unroll
        for (int i = 0; i < OUT_F; ++i) {
            const int k = i * BLOCK + tid;
            __builtin_nontemporal_store(os[k], out + obase + k);
        }
    } else {
        const long ototal = (long)n_tokens * OUT_F;
        #pragma unroll
        for (int i = 0; i < OUT_F; ++i) {
            const int k = i * BLOCK + tid;
            const long gi = obase + k;
            if (gi < ototal) out[gi] = os[k];
        }
    }
}

extern "C" void kernel_launch(void* const* d_in, const int* in_sizes, int n_in,
                              void* d_out, int out_size, void* d_ws, size_t ws_size,
                              hipStream_t stream) {
    const float* x    = (const float*)d_in[0];   // [N, 5]
    const float* wgt  = (const float*)d_in[1];   // [10, 5]
    const float* bias = (const float*)d_in[2];   // [10]
    float* out = (float*)d_out;                  // [N, 10]

    const int n_tokens = in_sizes[0] / IN_F;          // 4,000,000
    const int blocks   = (n_tokens + TOK - 1) / TOK;  // 15625, no tail

    qlinear_kernel<<<blocks, BLOCK, 0, stream>>>(x, wgt, bias, out, n_tokens);
}